// Round 13
// baseline (155.659 us; speedup 1.0000x reference)
//
#include <hip/hip_runtime.h>

// 4 lanes per batch element (one quad); 4 hidden units per lane as TWO v2f
// halves (a: units 4u,4u+1; b: units 4u+2,4u+3). 16 elements per wave ->
// per-element issue nearly halves vs LPE=8; reduce needs only 2 DPP stages.
// Algorithm identical to R9: q-state 2nd-order Taylor advance, exact exp2+rcp
// resync every RS steps, phase-barrier load/compute/store chunks.
#define LPE 4
#define CH 16   // steps per prefetch chunk
#define RS 8    // resync period (must divide CH; RS=8 numerics validated R11)

typedef float v2f __attribute__((ext_vector_type(2)));

#if __has_builtin(__builtin_amdgcn_exp2f)
  #define EXP2F(x) __builtin_amdgcn_exp2f(x)
#else
  #define EXP2F(x) exp2f(x)
#endif
#if __has_builtin(__builtin_amdgcn_rcpf)
  #define RCPF(x) __builtin_amdgcn_rcpf(x)
#else
  #define RCPF(x) (1.0f/(x))
#endif

template<int CTRL>
__device__ __forceinline__ float dpp_add(float x) {
    int y = __builtin_amdgcn_update_dpp(0, __float_as_int(x), CTRL, 0xF, 0xF, true);
    return x + __int_as_float(y);
}

__device__ __forceinline__ v2f vfma(v2f a, v2f b, v2f c) {
#if __has_builtin(__builtin_elementwise_fma)
    return __builtin_elementwise_fma(a, b, c);
#else
    v2f r; r.x = fmaf(a.x, b.x, c.x); r.y = fmaf(a.y, b.y, c.y); return r;
#endif
}
__device__ __forceinline__ v2f splat(float x) { v2f v; v.x = x; v.y = x; return v; }

#define MEMBAR() __asm__ __volatile__("" ::: "memory")

struct UnitW { float w0, w3, w4, cc, v3, v4; };

__global__ __launch_bounds__(256, 1) void ode_scan(
    const float* __restrict__ t,
    const float* __restrict__ Vs,
    const float* __restrict__ Tm,
    const float* __restrict__ C0,
    const float* __restrict__ R0,
    const float* __restrict__ W1,   // (5,10)
    const float* __restrict__ b1,   // (10)
    const float* __restrict__ W2,   // (10,5)
    const float* __restrict__ b2,   // (5)
    float* __restrict__ out,        // (B, N+1, 2)
    int B, int N)
{
    int tid = blockIdx.x * blockDim.x + threadIdx.x;
    int e = tid >> 2;      // element (one quad per element)
    int u = tid & 3;       // lane within quad; units 4u..4u+3
    if (e >= B) return;

    const float S   = 2.88539008177792681472f;   // 2*log2(e)
    const float LN2 = 0.69314718055994530942f;
    float Vv = Vs[e], Tv = Tm[e];

    // per-unit weight fill (value-returning; vector elems can't bind to refs)
    auto unitw = [&](int j) -> UnitW {
        UnitW w;
        if (j < 10) {
            w.w0 = S*W1[j]; w.w3 = S*W1[30+j]; w.w4 = S*W1[40+j];
            w.cc = S*fmaf(Vv, W1[10+j], fmaf(Tv, W1[20+j], b1[j]));
            w.v3 = -2.0f*W2[5*j+3]; w.v4 = -2.0f*W2[5*j+4];
        } else if (j == 10) {
            // constant unit: a=-60 -> z=2^-60 -> 1+z==1.0f -> r==1.0 exactly;
            // fast advance: s = r*r - r = 0 -> q,r stay exactly constant.
            w.w0 = 0.f; w.w3 = 0.f; w.w4 = 0.f; w.cc = -60.f;
            float c3 = b2[3], c4 = b2[4];
            for (int k = 0; k < 10; ++k) { c3 += W2[5*k+3]; c4 += W2[5*k+4]; }
            w.v3 = c3; w.v4 = c4;
        } else {
            w.w0 = 0.f; w.w3 = 0.f; w.w4 = 0.f; w.cc = -60.f; w.v3 = 0.f; w.v4 = 0.f;
        }
        return w;
    };

    UnitW u0 = unitw(4*u+0), u1 = unitw(4*u+1), u2 = unitw(4*u+2), u3 = unitw(4*u+3);

    v2f W0A, W3A, W4A, CCA, V3A, V4A;   // units 4u, 4u+1
    v2f W0B, W3B, W4B, CCB, V3B, V4B;   // units 4u+2, 4u+3
    W0A.x=u0.w0; W0A.y=u1.w0;  W3A.x=u0.w3; W3A.y=u1.w3;
    W4A.x=u0.w4; W4A.y=u1.w4;  CCA.x=u0.cc; CCA.y=u1.cc;
    V3A.x=u0.v3; V3A.y=u1.v3;  V4A.x=u0.v4; V4A.y=u1.v4;
    W0B.x=u2.w0; W0B.y=u3.w0;  W3B.x=u2.w3; W3B.y=u3.w3;
    W4B.x=u2.w4; W4B.y=u3.w4;  CCB.x=u2.cc; CCB.y=u3.cc;
    V3B.x=u2.v3; V3B.y=u3.v3;  V4B.x=u2.v4; V4B.y=u3.v4;

    const v2f ONEv = splat(1.0f);
    // ln2-scaled weights for the a-space advance (dl = ln2 * delta_a)
    v2f W0LA = splat(LN2) * W0A, W3LA = splat(LN2) * W3A, W4LA = splat(LN2) * W4A;
    v2f W0LB = splat(LN2) * W0B, W3LB = splat(LN2) * W3B, W4LB = splat(LN2) * W4B;

    float Cap = C0[e], Res = R0[e];
    const float* trow = t + (size_t)e * (N + 1);
    float* orow = out + (size_t)e * (size_t)(N + 1) * 2;
    *(float2*)orow = make_float2(Cap, Res);
    float tprev = trow[0];

    v2f ra = ONEv, rb = ONEv;
    v2f q3a = V3A, q3b = V3B, q4a = V4A, q4b = V4B;   // valid after first slow

    // reduce over the quad: pair-tree (pk add + scalar add) then 2 DPP stages
    auto reduce2 = [&](float& p3, float& p4) {
        v2f c3 = q3a + q3b;
        v2f c4 = q4a + q4b;
        p3 = c3.x + c3.y;
        p4 = c4.x + c4.y;
        p3 = dpp_add<0xB1>(p3);  p4 = dpp_add<0xB1>(p4);   // xor 1
        p3 = dpp_add<0x4E>(p3);  p4 = dpp_add<0x4E>(p4);   // xor 2
    };

    // exact step: recompute r,q from the current state -> kills drift
    auto slow_step = [&](float tn, float2& dst) {
        v2f TPa = vfma(splat(tprev), W0A, CCA);
        v2f TPb = vfma(splat(tprev), W0B, CCB);
        v2f Aa  = vfma(splat(Res), W4A, vfma(splat(Cap), W3A, TPa));
        v2f Ab  = vfma(splat(Res), W4B, vfma(splat(Cap), W3B, TPb));
        v2f za; za.x = EXP2F(Aa.x); za.y = EXP2F(Aa.y);
        v2f zb; zb.x = EXP2F(Ab.x); zb.y = EXP2F(Ab.y);
        v2f da = za + ONEv, db = zb + ONEv;
        v2f na; na.x = RCPF(da.x); na.y = RCPF(da.y);
        v2f nb; nb.x = RCPF(db.x); nb.y = RCPF(db.y);
        ra = na; rb = nb;
        q3a = ra * V3A; q3b = rb * V3B;
        q4a = ra * V4A; q4b = rb * V4B;
        float h = tn - tprev;
        float p3, p4;
        reduce2(p3, p4);
        Cap = fmaf(h, p3, Cap);
        Res = fmaf(h, p4, Res);
        tprev = tn;
        dst = make_float2(Cap, Res);
    };

    // incremental step: 2nd-order Taylor advance of q,r in a-space (R9 math)
    auto fast_step = [&](float tn, float2& dst) {
        float h = tn - tprev;
        v2f sa  = vfma(ra, ra, -ra), sb  = vfma(rb, rb, -rb);
        v2f rma = ra + splat(-0.5f), rmb = rb + splat(-0.5f);
        float p3, p4;
        reduce2(p3, p4);
        Cap = fmaf(h, p3, Cap);
        Res = fmaf(h, p4, Res);
        tprev = tn;
        dst = make_float2(Cap, Res);
        v2f Ga = vfma(splat(p3), W3LA, vfma(splat(p4), W4LA, W0LA));
        v2f Gb = vfma(splat(p3), W3LB, vfma(splat(p4), W4LB, W0LB));
        v2f dla = splat(h) * Ga, dlb = splat(h) * Gb;
        v2f fa  = vfma(dla, rma, ONEv), fb = vfma(dlb, rmb, ONEv);
        v2f ua  = (dla * sa) * fa,  ub = (dlb * sb) * fb;
        q3a = vfma(ua, V3A, q3a);  q3b = vfma(ub, V3B, q3b);
        q4a = vfma(ua, V4A, q4a);  q4b = vfma(ub, V4B, q4b);
        ra  = ra + ua;             rb  = rb + ub;
    };

    int i = 1;
    if (N >= 2*CH) {
        float rawA[CH], rawB[CH];
        float2 keep[CH];
        int nch = N / CH;
        int npair = nch / 2;
        int lim = N + 1 - CH;

#pragma unroll
        for (int m = 0; m < CH; ++m) rawA[m] = trow[1 + m];   // chunk 0
        MEMBAR();

        float2* op = (float2*)orow + 1;
        for (int p = 0; p < npair; ++p) {
            int c = 2*p;
            {   // loads for chunk c+1 -> compute chunk c -> store burst
                int base = (c + 1)*CH + 1; if (base > lim) base = lim;
                const float* lp = trow + base;
#pragma unroll
                for (int m = 0; m < CH; ++m) rawB[m] = lp[m];
                MEMBAR();
#pragma unroll
                for (int m = 0; m < CH; ++m) {
                    if ((m % RS) == 0) slow_step(rawA[m], keep[m]);
                    else               fast_step(rawA[m], keep[m]);
                }
                MEMBAR();
#pragma unroll
                for (int m = 0; m < CH; ++m) op[m] = keep[m];
                op += CH;
            }
            {   // loads for chunk c+2 -> compute chunk c+1 -> store burst
                int base = (c + 2)*CH + 1; if (base > lim) base = lim;
                const float* lp = trow + base;
#pragma unroll
                for (int m = 0; m < CH; ++m) rawA[m] = lp[m];
                MEMBAR();
#pragma unroll
                for (int m = 0; m < CH; ++m) {
                    if ((m % RS) == 0) slow_step(rawB[m], keep[m]);
                    else               fast_step(rawB[m], keep[m]);
                }
                MEMBAR();
#pragma unroll
                for (int m = 0; m < CH; ++m) op[m] = keep[m];
                op += CH;
            }
        }
        i = 2*CH*npair + 1;
    }
    // scalar tail (not hit for N=2048): all exact steps
    for (; i <= N; ++i) {
        slow_step(trow[i], *(float2*)(orow + 2*(size_t)i));
    }
}

extern "C" void kernel_launch(void* const* d_in, const int* in_sizes, int n_in,
                              void* d_out, int out_size, void* d_ws, size_t ws_size,
                              hipStream_t stream) {
    const float* t  = (const float*)d_in[0];
    const float* Vs = (const float*)d_in[1];
    const float* Tm = (const float*)d_in[2];
    const float* C0 = (const float*)d_in[3];
    const float* R0 = (const float*)d_in[4];
    const float* W1 = (const float*)d_in[5];
    const float* b1 = (const float*)d_in[6];
    const float* W2 = (const float*)d_in[7];
    const float* b2 = (const float*)d_in[8];
    float* out = (float*)d_out;

    int B = in_sizes[1];
    int N = in_sizes[0] / B - 1;

    int threads = B * LPE;
    dim3 block(256);
    dim3 grid((threads + 255) / 256);
    hipLaunchKernelGGL(ode_scan, grid, block, 0, stream,
                       t, Vs, Tm, C0, R0, W1, b1, W2, b2, out, B, N);
}

// Round 14
// 148.341 us; speedup vs baseline: 1.0493x; 1.0493x over previous
//
#include <hip/hip_runtime.h>

// 8 lanes per batch element; 2 hidden units per lane packed as float2 (VOP3P).
// All steps are uniform Taylor-advance fast steps (R9 math). The exact
// exp2+rcp resync is PIPELINED: launched at the start of the last step of
// each 16-step chunk (inputs are the bit-exact Cap/Res/tprev), completes
// during that step's wall, and is swapped in at step 0 of the next chunk
// via r = rpre + uf_last (bridge error ~1e-7). Transcendentals never sit
// on the critical chain. R9's phase-barrier load/compute/store pipeline.
#define LPE 8
#define CH 16   // steps per prefetch chunk == resync period

typedef float v2f __attribute__((ext_vector_type(2)));

#if __has_builtin(__builtin_amdgcn_exp2f)
  #define EXP2F(x) __builtin_amdgcn_exp2f(x)
#else
  #define EXP2F(x) exp2f(x)
#endif
#if __has_builtin(__builtin_amdgcn_rcpf)
  #define RCPF(x) __builtin_amdgcn_rcpf(x)
#else
  #define RCPF(x) (1.0f/(x))
#endif

template<int CTRL>
__device__ __forceinline__ float dpp_add(float x) {
    int y = __builtin_amdgcn_update_dpp(0, __float_as_int(x), CTRL, 0xF, 0xF, true);
    return x + __int_as_float(y);
}

__device__ __forceinline__ v2f vfma(v2f a, v2f b, v2f c) {
#if __has_builtin(__builtin_elementwise_fma)
    return __builtin_elementwise_fma(a, b, c);
#else
    v2f r; r.x = fmaf(a.x, b.x, c.x); r.y = fmaf(a.y, b.y, c.y); return r;
#endif
}
__device__ __forceinline__ v2f splat(float x) { v2f v; v.x = x; v.y = x; return v; }

#define MEMBAR() __asm__ __volatile__("" ::: "memory")

__global__ __launch_bounds__(256, 1) void ode_scan(
    const float* __restrict__ t,
    const float* __restrict__ Vs,
    const float* __restrict__ Tm,
    const float* __restrict__ C0,
    const float* __restrict__ R0,
    const float* __restrict__ W1,   // (5,10)
    const float* __restrict__ b1,   // (10)
    const float* __restrict__ W2,   // (10,5)
    const float* __restrict__ b2,   // (5)
    float* __restrict__ out,        // (B, N+1, 2)
    int B, int N)
{
    int tid = blockIdx.x * blockDim.x + threadIdx.x;
    int e = tid >> 3;
    int u = tid & 7;
    if (e >= B) return;

    const float S   = 2.88539008177792681472f;   // 2*log2(e)
    const float LN2 = 0.69314718055994530942f;
    float Vv = Vs[e], Tv = Tm[e];

    // Packed per-lane weights for hidden units j0=2u (x), j1=2u+1 (y).
    v2f W0p, W3p, W4p, CCp, V3p, V4p;
    {
        int j0 = 2*u, j1 = 2*u + 1;
        if (j0 < 10) {
            W0p.x = S*W1[j0]; W3p.x = S*W1[30+j0]; W4p.x = S*W1[40+j0];
            CCp.x = S*fmaf(Vv, W1[10+j0], fmaf(Tv, W1[20+j0], b1[j0]));
            V3p.x = -2.0f*W2[5*j0+3]; V4p.x = -2.0f*W2[5*j0+4];
        } else { W0p.x=0.f; W3p.x=0.f; W4p.x=0.f; CCp.x=-60.f; V3p.x=0.f; V4p.x=0.f; }
        if (j1 < 10) {
            W0p.y = S*W1[j1]; W3p.y = S*W1[30+j1]; W4p.y = S*W1[40+j1];
            CCp.y = S*fmaf(Vv, W1[10+j1], fmaf(Tv, W1[20+j1], b1[j1]));
            V3p.y = -2.0f*W2[5*j1+3]; V4p.y = -2.0f*W2[5*j1+4];
        } else { W0p.y=0.f; W3p.y=0.f; W4p.y=0.f; CCp.y=-60.f; V3p.y=0.f; V4p.y=0.f; }
        if (j0 == 10) {
            // constant unit: a=-60 -> z=2^-60 -> 1+z==1.0f -> r==1.0 exactly;
            // advance: s = r*r - r = 0 -> q3,q4,r stay exactly constant;
            // resync: rpre == 1.0 exactly, uf == 0 -> swap keeps r == 1.0.
            float c3 = b2[3], c4 = b2[4];
            for (int j = 0; j < 10; ++j) { c3 += W2[5*j+3]; c4 += W2[5*j+4]; }
            V3p.x = c3; V4p.x = c4;
        }
    }

    const v2f ONEv = splat(1.0f);
    // ln2-scaled weights for the a-space advance (dl = ln2 * delta_a)
    v2f W0a = splat(LN2) * W0p;
    v2f W3a = splat(LN2) * W3p;
    v2f W4a = splat(LN2) * W4p;

    float Cap = C0[e], Res = R0[e];
    const float* trow = t + (size_t)e * (N + 1);
    float* orow = out + (size_t)e * (size_t)(N + 1) * 2;
    *(float2*)orow = make_float2(Cap, Res);
    float tprev = trow[0];

    // exact r for the CURRENT (tprev, Cap, Res) state
    auto exact_r = [&]() -> v2f {
        v2f TP = vfma(splat(tprev), W0p, CCp);
        v2f A  = vfma(splat(Res), W4p, vfma(splat(Cap), W3p, TP));
        v2f zz; zz.x = EXP2F(A.x); zz.y = EXP2F(A.y);
        v2f dd = zz + ONEv;
        v2f rr; rr.x = RCPF(dd.x); rr.y = RCPF(dd.y);
        return rr;
    };

    v2f r = ONEv, q3 = V3p, q4 = V4p;   // overwritten at first swap
    v2f rpre = exact_r();                // exact r entering step 1
    v2f ufp  = splat(0.0f);              // bridge update (none yet)

    auto reduce2 = [&](float& p3, float& p4) {
        p3 = q3.x + q3.y;
        p4 = q4.x + q4.y;
        p3 = dpp_add<0xB1>(p3);  p4 = dpp_add<0xB1>(p4);
        p3 = dpp_add<0x4E>(p3);  p4 = dpp_add<0x4E>(p4);
        p3 = dpp_add<0x141>(p3); p4 = dpp_add<0x141>(p4);
    };

    // uniform step. swap: install pipelined exact base (step 0 of a chunk).
    // prep: launch next resync from the START-of-step state, save uf at end
    // (step CH-1 of a chunk).
    auto step = [&](float tn, float2& dst, bool swap, bool prep) {
        v2f r_launch;
        if (prep) r_launch = exact_r();   // uses pre-update tprev/Cap/Res
        if (swap) {
            r  = rpre + ufp;              // exact base + bridge
            q3 = r * V3p;
            q4 = r * V4p;
        }
        float h = tn - tprev;
        v2f s   = vfma(r, r, -r);
        v2f rm  = r + splat(-0.5f);
        float p3, p4;
        reduce2(p3, p4);
        Cap = fmaf(h, p3, Cap);
        Res = fmaf(h, p4, Res);
        tprev = tn;
        dst = make_float2(Cap, Res);
        v2f G  = vfma(splat(p3), W3a, vfma(splat(p4), W4a, W0a));
        v2f dl = splat(h) * G;
        v2f f  = vfma(dl, rm, ONEv);
        v2f uf = (dl * s) * f;
        q3 = vfma(uf, V3p, q3);
        q4 = vfma(uf, V4p, q4);
        r  = r + uf;
        if (prep) { rpre = r_launch; ufp = uf; }
    };

    // fully exact fallback step (tail only)
    auto slow_step = [&](float tn, float2& dst) {
        r  = exact_r();
        q3 = r * V3p;
        q4 = r * V4p;
        float h = tn - tprev;
        float p3, p4;
        reduce2(p3, p4);
        Cap = fmaf(h, p3, Cap);
        Res = fmaf(h, p4, Res);
        tprev = tn;
        dst = make_float2(Cap, Res);
    };

    int i = 1;
    if (N >= 2*CH) {
        float rawA[CH], rawB[CH];
        float2 keep[CH];
        int nch = N / CH;
        int npair = nch / 2;
        int lim = N + 1 - CH;

#pragma unroll
        for (int m = 0; m < CH; ++m) rawA[m] = trow[1 + m];   // chunk 0
        MEMBAR();

        float2* op = (float2*)orow + 1;
        for (int p = 0; p < npair; ++p) {
            int c = 2*p;
            {   // loads for chunk c+1 -> compute chunk c -> store burst
                int base = (c + 1)*CH + 1; if (base > lim) base = lim;
                const float* lp = trow + base;
#pragma unroll
                for (int m = 0; m < CH; ++m) rawB[m] = lp[m];
                MEMBAR();
#pragma unroll
                for (int m = 0; m < CH; ++m)
                    step(rawA[m], keep[m], m == 0, m == CH-1);
                MEMBAR();
#pragma unroll
                for (int m = 0; m < CH; ++m) op[m] = keep[m];
                op += CH;
            }
            {   // loads for chunk c+2 -> compute chunk c+1 -> store burst
                int base = (c + 2)*CH + 1; if (base > lim) base = lim;
                const float* lp = trow + base;
#pragma unroll
                for (int m = 0; m < CH; ++m) rawA[m] = lp[m];
                MEMBAR();
#pragma unroll
                for (int m = 0; m < CH; ++m)
                    step(rawB[m], keep[m], m == 0, m == CH-1);
                MEMBAR();
#pragma unroll
                for (int m = 0; m < CH; ++m) op[m] = keep[m];
                op += CH;
            }
        }
        i = 2*CH*npair + 1;
    }
    // scalar tail (not hit for N=2048): fully exact steps
    for (; i <= N; ++i) {
        slow_step(trow[i], *(float2*)(orow + 2*(size_t)i));
    }
}

extern "C" void kernel_launch(void* const* d_in, const int* in_sizes, int n_in,
                              void* d_out, int out_size, void* d_ws, size_t ws_size,
                              hipStream_t stream) {
    const float* t  = (const float*)d_in[0];
    const float* Vs = (const float*)d_in[1];
    const float* Tm = (const float*)d_in[2];
    const float* C0 = (const float*)d_in[3];
    const float* R0 = (const float*)d_in[4];
    const float* W1 = (const float*)d_in[5];
    const float* b1 = (const float*)d_in[6];
    const float* W2 = (const float*)d_in[7];
    const float* b2 = (const float*)d_in[8];
    float* out = (float*)d_out;

    int B = in_sizes[1];
    int N = in_sizes[0] / B - 1;

    int threads = B * LPE;
    dim3 block(256);
    dim3 grid((threads + 255) / 256);
    hipLaunchKernelGGL(ode_scan, grid, block, 0, stream,
                       t, Vs, Tm, C0, R0, W1, b1, W2, b2, out, B, N);
}

// Round 15
// 79.874 us; speedup vs baseline: 1.9488x; 1.8572x over previous
//
#include <hip/hip_runtime.h>

// 8 lanes per batch element; 2 hidden units per lane packed as float2.
// Per-step work is a SCALAR 2x2 linear recurrence on (p3,p4) (the reduced MLP
// outputs): dp = h*(C0 + C*p), where the six C coefficients and exact p3,p4
// are rebuilt every K=8 steps from the exact per-unit state (exp2+rcp +
// 8 DPP-reduces). Fast steps: ~10 scalar instrs, 3-fma chain, no DPP.
// R9's phase-barrier load/compute/store chunk pipeline.
#define LPE 8
#define CH 16   // steps per prefetch chunk
#define KR 8    // refresh period (divides CH)

typedef float v2f __attribute__((ext_vector_type(2)));

#if __has_builtin(__builtin_amdgcn_exp2f)
  #define EXP2F(x) __builtin_amdgcn_exp2f(x)
#else
  #define EXP2F(x) exp2f(x)
#endif
#if __has_builtin(__builtin_amdgcn_rcpf)
  #define RCPF(x) __builtin_amdgcn_rcpf(x)
#else
  #define RCPF(x) (1.0f/(x))
#endif

template<int CTRL>
__device__ __forceinline__ float dpp_add(float x) {
    int y = __builtin_amdgcn_update_dpp(0, __float_as_int(x), CTRL, 0xF, 0xF, true);
    return x + __int_as_float(y);
}
// butterfly sum over aligned 8-lane groups; all lanes get the total
__device__ __forceinline__ float red8(float v) {
    v = dpp_add<0xB1>(v);
    v = dpp_add<0x4E>(v);
    v = dpp_add<0x141>(v);
    return v;
}

__device__ __forceinline__ v2f vfma(v2f a, v2f b, v2f c) {
#if __has_builtin(__builtin_elementwise_fma)
    return __builtin_elementwise_fma(a, b, c);
#else
    v2f r; r.x = fmaf(a.x, b.x, c.x); r.y = fmaf(a.y, b.y, c.y); return r;
#endif
}
__device__ __forceinline__ v2f splat(float x) { v2f v; v.x = x; v.y = x; return v; }

#define MEMBAR() __asm__ __volatile__("" ::: "memory")

__global__ __launch_bounds__(256, 1) void ode_scan(
    const float* __restrict__ t,
    const float* __restrict__ Vs,
    const float* __restrict__ Tm,
    const float* __restrict__ C0,
    const float* __restrict__ R0,
    const float* __restrict__ W1,   // (5,10)
    const float* __restrict__ b1,   // (10)
    const float* __restrict__ W2,   // (10,5)
    const float* __restrict__ b2,   // (5)
    float* __restrict__ out,        // (B, N+1, 2)
    int B, int N)
{
    int tid = blockIdx.x * blockDim.x + threadIdx.x;
    int e = tid >> 3;
    int u = tid & 7;
    if (e >= B) return;

    const float S   = 2.88539008177792681472f;   // 2*log2(e)
    const float LN2 = 0.69314718055994530942f;
    float Vv = Vs[e], Tv = Tm[e];

    // Packed per-lane weights for hidden units j0=2u (x), j1=2u+1 (y).
    v2f W0p, W3p, W4p, CCp, V3p, V4p;
    {
        int j0 = 2*u, j1 = 2*u + 1;
        if (j0 < 10) {
            W0p.x = S*W1[j0]; W3p.x = S*W1[30+j0]; W4p.x = S*W1[40+j0];
            CCp.x = S*fmaf(Vv, W1[10+j0], fmaf(Tv, W1[20+j0], b1[j0]));
            V3p.x = -2.0f*W2[5*j0+3]; V4p.x = -2.0f*W2[5*j0+4];
        } else { W0p.x=0.f; W3p.x=0.f; W4p.x=0.f; CCp.x=-60.f; V3p.x=0.f; V4p.x=0.f; }
        if (j1 < 10) {
            W0p.y = S*W1[j1]; W3p.y = S*W1[30+j1]; W4p.y = S*W1[40+j1];
            CCp.y = S*fmaf(Vv, W1[10+j1], fmaf(Tv, W1[20+j1], b1[j1]));
            V3p.y = -2.0f*W2[5*j1+3]; V4p.y = -2.0f*W2[5*j1+4];
        } else { W0p.y=0.f; W3p.y=0.f; W4p.y=0.f; CCp.y=-60.f; V3p.y=0.f; V4p.y=0.f; }
        if (j0 == 10) {
            // constant unit: a=-60 -> r==1.0 exactly, s==0 -> contributes the
            // exact constant to p3,p4 at refresh and ZERO to all C's.
            float c3 = b2[3], c4 = b2[4];
            for (int j = 0; j < 10; ++j) { c3 += W2[5*j+3]; c4 += W2[5*j+4]; }
            V3p.x = c3; V4p.x = c4;
        }
    }

    const v2f ONEv = splat(1.0f);
    // Static coefficient products: M[k][c] = ln2*Wk * Vc  (per-lane v2f)
    v2f W0a = splat(LN2) * W0p, W3a = splat(LN2) * W3p, W4a = splat(LN2) * W4p;
    v2f M30 = W0a * V3p, M33 = W3a * V3p, M34 = W4a * V3p;
    v2f M40 = W0a * V4p, M43 = W3a * V4p, M44 = W4a * V4p;

    float Cap = C0[e], Res = R0[e];
    const float* trow = t + (size_t)e * (N + 1);
    float* orow = out + (size_t)e * (size_t)(N + 1) * 2;
    *(float2*)orow = make_float2(Cap, Res);
    float tprev = trow[0];

    // broadcast scalar state (uniform across the 8-lane group)
    float p3 = 0.f, p4 = 0.f;
    float C30 = 0.f, C33 = 0.f, C34 = 0.f, C40 = 0.f, C43 = 0.f, C44 = 0.f;

    // refresh: exact per-unit r from the bit-exact (tprev,Cap,Res) state,
    // then reduce exact p3,p4 and the six C coefficients.
    auto refresh = [&]() {
        v2f TP = vfma(splat(tprev), W0p, CCp);
        v2f A  = vfma(splat(Res), W4p, vfma(splat(Cap), W3p, TP));
        v2f zz; zz.x = EXP2F(A.x); zz.y = EXP2F(A.y);
        v2f dd = zz + ONEv;
        v2f rr; rr.x = RCPF(dd.x); rr.y = RCPF(dd.y);
        v2f ss = vfma(rr, rr, -rr);      // s = r^2 - r
        v2f l3 = rr * V3p, l4 = rr * V4p;
        v2f k30 = ss * M30, k33 = ss * M33, k34 = ss * M34;
        v2f k40 = ss * M40, k43 = ss * M43, k44 = ss * M44;
        p3  = red8(l3.x + l3.y);
        p4  = red8(l4.x + l4.y);
        C30 = red8(k30.x + k30.y);
        C33 = red8(k33.x + k33.y);
        C34 = red8(k34.x + k34.y);
        C40 = red8(k40.x + k40.y);
        C43 = red8(k43.x + k43.y);
        C44 = red8(k44.x + k44.y);
    };

    // fast step: scalar 2x2 linear recurrence; 3-fma critical chain, no DPP.
    auto fstep = [&](float tn, float2& dst) {
        float h  = tn - tprev;
        float u3 = fmaf(p4, C34, fmaf(p3, C33, C30));
        float u4 = fmaf(p4, C44, fmaf(p3, C43, C40));
        Cap = fmaf(h, p3, Cap);
        Res = fmaf(h, p4, Res);
        p3  = fmaf(h, u3, p3);
        p4  = fmaf(h, u4, p4);
        tprev = tn;
        dst = make_float2(Cap, Res);
    };

    int i = 1;
    if (N >= 2*CH) {
        float rawA[CH], rawB[CH];
        float2 keep[CH];
        int nch = N / CH;
        int npair = nch / 2;
        int lim = N + 1 - CH;

#pragma unroll
        for (int m = 0; m < CH; ++m) rawA[m] = trow[1 + m];   // chunk 0
        MEMBAR();

        float2* op = (float2*)orow + 1;
        for (int p = 0; p < npair; ++p) {
            int c = 2*p;
            {   // loads for chunk c+1 -> compute chunk c -> store burst
                int base = (c + 1)*CH + 1; if (base > lim) base = lim;
                const float* lp = trow + base;
#pragma unroll
                for (int m = 0; m < CH; ++m) rawB[m] = lp[m];
                MEMBAR();
#pragma unroll
                for (int m = 0; m < CH; ++m) {
                    if ((m % KR) == 0) refresh();
                    fstep(rawA[m], keep[m]);
                }
                MEMBAR();
#pragma unroll
                for (int m = 0; m < CH; ++m) op[m] = keep[m];
                op += CH;
            }
            {   // loads for chunk c+2 -> compute chunk c+1 -> store burst
                int base = (c + 2)*CH + 1; if (base > lim) base = lim;
                const float* lp = trow + base;
#pragma unroll
                for (int m = 0; m < CH; ++m) rawA[m] = lp[m];
                MEMBAR();
#pragma unroll
                for (int m = 0; m < CH; ++m) {
                    if ((m % KR) == 0) refresh();
                    fstep(rawB[m], keep[m]);
                }
                MEMBAR();
#pragma unroll
                for (int m = 0; m < CH; ++m) op[m] = keep[m];
                op += CH;
            }
        }
        i = 2*CH*npair + 1;
    }
    // scalar tail (not hit for N=2048): refresh every step (exact)
    for (; i <= N; ++i) {
        refresh();
        fstep(trow[i], *(float2*)(orow + 2*(size_t)i));
    }
}

extern "C" void kernel_launch(void* const* d_in, const int* in_sizes, int n_in,
                              void* d_out, int out_size, void* d_ws, size_t ws_size,
                              hipStream_t stream) {
    const float* t  = (const float*)d_in[0];
    const float* Vs = (const float*)d_in[1];
    const float* Tm = (const float*)d_in[2];
    const float* C0 = (const float*)d_in[3];
    const float* R0 = (const float*)d_in[4];
    const float* W1 = (const float*)d_in[5];
    const float* b1 = (const float*)d_in[6];
    const float* W2 = (const float*)d_in[7];
    const float* b2 = (const float*)d_in[8];
    float* out = (float*)d_out;

    int B = in_sizes[1];
    int N = in_sizes[0] / B - 1;

    int threads = B * LPE;
    dim3 block(256);
    dim3 grid((threads + 255) / 256);
    hipLaunchKernelGGL(ode_scan, grid, block, 0, stream,
                       t, Vs, Tm, C0, R0, W1, b1, W2, b2, out, B, N);
}

// Round 16
// 79.220 us; speedup vs baseline: 1.9649x; 1.0083x over previous
//
#include <hip/hip_runtime.h>

// 8 lanes per batch element; 2 hidden units per lane packed as float2.
// Per-step work: PACKED scalar 2x2 linear recurrence on pv=(p3,p4):
//   u = C0 + C3*p3 + C4*p4 (pk_fma with op_sel splats), state += h*...
// The six C coefficients and exact p3,p4 are rebuilt once per chunk (KR=16)
// from the exact per-unit state (exp2+rcp + 8 DPP-reduces).
// R9's phase-barrier load/compute/store chunk pipeline.
#define LPE 8
#define CH 16   // steps per prefetch chunk
#define KR 16   // refresh period (== CH; refresh at chunk head)

typedef float v2f __attribute__((ext_vector_type(2)));

#if __has_builtin(__builtin_amdgcn_exp2f)
  #define EXP2F(x) __builtin_amdgcn_exp2f(x)
#else
  #define EXP2F(x) exp2f(x)
#endif
#if __has_builtin(__builtin_amdgcn_rcpf)
  #define RCPF(x) __builtin_amdgcn_rcpf(x)
#else
  #define RCPF(x) (1.0f/(x))
#endif

template<int CTRL>
__device__ __forceinline__ float dpp_add(float x) {
    int y = __builtin_amdgcn_update_dpp(0, __float_as_int(x), CTRL, 0xF, 0xF, true);
    return x + __int_as_float(y);
}
// butterfly sum over aligned 8-lane groups; all lanes get the total
__device__ __forceinline__ float red8(float v) {
    v = dpp_add<0xB1>(v);
    v = dpp_add<0x4E>(v);
    v = dpp_add<0x141>(v);
    return v;
}

__device__ __forceinline__ v2f vfma(v2f a, v2f b, v2f c) {
#if __has_builtin(__builtin_elementwise_fma)
    return __builtin_elementwise_fma(a, b, c);
#else
    v2f r; r.x = fmaf(a.x, b.x, c.x); r.y = fmaf(a.y, b.y, c.y); return r;
#endif
}
__device__ __forceinline__ v2f splat(float x) { v2f v; v.x = x; v.y = x; return v; }

#define MEMBAR() __asm__ __volatile__("" ::: "memory")

__global__ __launch_bounds__(256, 1) void ode_scan(
    const float* __restrict__ t,
    const float* __restrict__ Vs,
    const float* __restrict__ Tm,
    const float* __restrict__ C0,
    const float* __restrict__ R0,
    const float* __restrict__ W1,   // (5,10)
    const float* __restrict__ b1,   // (10)
    const float* __restrict__ W2,   // (10,5)
    const float* __restrict__ b2,   // (5)
    float* __restrict__ out,        // (B, N+1, 2)
    int B, int N)
{
    int tid = blockIdx.x * blockDim.x + threadIdx.x;
    int e = tid >> 3;
    int u = tid & 7;
    if (e >= B) return;

    const float S   = 2.88539008177792681472f;   // 2*log2(e)
    const float LN2 = 0.69314718055994530942f;
    float Vv = Vs[e], Tv = Tm[e];

    // Packed per-lane weights for hidden units j0=2u (x), j1=2u+1 (y).
    v2f W0p, W3p, W4p, CCp, V3p, V4p;
    {
        int j0 = 2*u, j1 = 2*u + 1;
        if (j0 < 10) {
            W0p.x = S*W1[j0]; W3p.x = S*W1[30+j0]; W4p.x = S*W1[40+j0];
            CCp.x = S*fmaf(Vv, W1[10+j0], fmaf(Tv, W1[20+j0], b1[j0]));
            V3p.x = -2.0f*W2[5*j0+3]; V4p.x = -2.0f*W2[5*j0+4];
        } else { W0p.x=0.f; W3p.x=0.f; W4p.x=0.f; CCp.x=-60.f; V3p.x=0.f; V4p.x=0.f; }
        if (j1 < 10) {
            W0p.y = S*W1[j1]; W3p.y = S*W1[30+j1]; W4p.y = S*W1[40+j1];
            CCp.y = S*fmaf(Vv, W1[10+j1], fmaf(Tv, W1[20+j1], b1[j1]));
            V3p.y = -2.0f*W2[5*j1+3]; V4p.y = -2.0f*W2[5*j1+4];
        } else { W0p.y=0.f; W3p.y=0.f; W4p.y=0.f; CCp.y=-60.f; V3p.y=0.f; V4p.y=0.f; }
        if (j0 == 10) {
            // constant unit: a=-60 -> r==1.0 exactly, s==0 -> contributes the
            // exact constant to p3,p4 at refresh and ZERO to all C's.
            float c3 = b2[3], c4 = b2[4];
            for (int j = 0; j < 10; ++j) { c3 += W2[5*j+3]; c4 += W2[5*j+4]; }
            V3p.x = c3; V4p.x = c4;
        }
    }

    const v2f ONEv = splat(1.0f);
    // Static coefficient products: M[k][c] = ln2*Wk * Vc  (per-lane v2f)
    v2f W0a = splat(LN2) * W0p, W3a = splat(LN2) * W3p, W4a = splat(LN2) * W4p;
    v2f M30 = W0a * V3p, M33 = W3a * V3p, M34 = W4a * V3p;
    v2f M40 = W0a * V4p, M43 = W3a * V4p, M44 = W4a * V4p;

    const float* trow = t + (size_t)e * (N + 1);
    float* orow = out + (size_t)e * (size_t)(N + 1) * 2;
    v2f CRv;                      // (Cap, Res) packed
    CRv.x = C0[e]; CRv.y = R0[e];
    *(float2*)orow = make_float2(CRv.x, CRv.y);
    float tprev = trow[0];

    // broadcast packed state (uniform across the 8-lane group)
    v2f pv  = splat(0.0f);                      // (p3, p4)
    v2f C0v = splat(0.0f), C3v = splat(0.0f), C4v = splat(0.0f);

    // refresh: exact per-unit r from the bit-exact (tprev,Cap,Res) state,
    // then reduce exact p3,p4 and the six C coefficients (packed).
    auto refresh = [&]() {
        v2f TP = vfma(splat(tprev), W0p, CCp);
        v2f A  = vfma(splat(CRv.y), W4p, vfma(splat(CRv.x), W3p, TP));
        v2f zz; zz.x = EXP2F(A.x); zz.y = EXP2F(A.y);
        v2f dd = zz + ONEv;
        v2f rr; rr.x = RCPF(dd.x); rr.y = RCPF(dd.y);
        v2f ss = vfma(rr, rr, -rr);      // s = r^2 - r
        v2f l3 = rr * V3p, l4 = rr * V4p;
        v2f k30 = ss * M30, k33 = ss * M33, k34 = ss * M34;
        v2f k40 = ss * M40, k43 = ss * M43, k44 = ss * M44;
        pv.x  = red8(l3.x + l3.y);
        pv.y  = red8(l4.x + l4.y);
        C0v.x = red8(k30.x + k30.y);
        C3v.x = red8(k33.x + k33.y);
        C4v.x = red8(k34.x + k34.y);
        C0v.y = red8(k40.x + k40.y);
        C3v.y = red8(k43.x + k43.y);
        C4v.y = red8(k44.x + k44.y);
    };

    // fast step: packed 2x2 linear recurrence; ~5 pk-VALU ops, 3-fma chain.
    auto fstep = [&](float tn, float2& dst) {
        float h  = tn - tprev;
        v2f hv   = splat(h);
        v2f uv   = vfma(splat(pv.y), C4v, vfma(splat(pv.x), C3v, C0v));
        CRv = vfma(hv, pv, CRv);
        pv  = vfma(hv, uv, pv);
        tprev = tn;
        dst = make_float2(CRv.x, CRv.y);
    };

    int i = 1;
    if (N >= 2*CH) {
        float rawA[CH], rawB[CH];
        float2 keep[CH];
        int nch = N / CH;
        int npair = nch / 2;
        int lim = N + 1 - CH;

#pragma unroll
        for (int m = 0; m < CH; ++m) rawA[m] = trow[1 + m];   // chunk 0
        MEMBAR();

        float2* op = (float2*)orow + 1;
        for (int p = 0; p < npair; ++p) {
            int c = 2*p;
            {   // loads for chunk c+1 -> compute chunk c -> store burst
                int base = (c + 1)*CH + 1; if (base > lim) base = lim;
                const float* lp = trow + base;
#pragma unroll
                for (int m = 0; m < CH; ++m) rawB[m] = lp[m];
                MEMBAR();
#pragma unroll
                for (int m = 0; m < CH; ++m) {
                    if ((m % KR) == 0) refresh();
                    fstep(rawA[m], keep[m]);
                }
                MEMBAR();
#pragma unroll
                for (int m = 0; m < CH; ++m) op[m] = keep[m];
                op += CH;
            }
            {   // loads for chunk c+2 -> compute chunk c+1 -> store burst
                int base = (c + 2)*CH + 1; if (base > lim) base = lim;
                const float* lp = trow + base;
#pragma unroll
                for (int m = 0; m < CH; ++m) rawA[m] = lp[m];
                MEMBAR();
#pragma unroll
                for (int m = 0; m < CH; ++m) {
                    if ((m % KR) == 0) refresh();
                    fstep(rawB[m], keep[m]);
                }
                MEMBAR();
#pragma unroll
                for (int m = 0; m < CH; ++m) op[m] = keep[m];
                op += CH;
            }
        }
        i = 2*CH*npair + 1;
    }
    // scalar tail (not hit for N=2048): refresh every step (exact)
    for (; i <= N; ++i) {
        refresh();
        fstep(trow[i], *(float2*)(orow + 2*(size_t)i));
    }
}

extern "C" void kernel_launch(void* const* d_in, const int* in_sizes, int n_in,
                              void* d_out, int out_size, void* d_ws, size_t ws_size,
                              hipStream_t stream) {
    const float* t  = (const float*)d_in[0];
    const float* Vs = (const float*)d_in[1];
    const float* Tm = (const float*)d_in[2];
    const float* C0 = (const float*)d_in[3];
    const float* R0 = (const float*)d_in[4];
    const float* W1 = (const float*)d_in[5];
    const float* b1 = (const float*)d_in[6];
    const float* W2 = (const float*)d_in[7];
    const float* b2 = (const float*)d_in[8];
    float* out = (float*)d_out;

    int B = in_sizes[1];
    int N = in_sizes[0] / B - 1;

    int threads = B * LPE;
    dim3 block(256);
    dim3 grid((threads + 255) / 256);
    hipLaunchKernelGGL(ode_scan, grid, block, 0, stream,
                       t, Vs, Tm, C0, R0, W1, b1, W2, b2, out, B, N);
}

// Round 17
// 68.769 us; speedup vs baseline: 2.2635x; 1.1520x over previous
//
#include <hip/hip_runtime.h>

// 8 lanes per batch element; 2 hidden units per lane packed as float2.
// Per-step: packed 2x2 linear recurrence on pv=(p3,p4); six C coefficients
// and exact p3,p4 rebuilt once per 16-step chunk (exp2+rcp + 8 DPP reduces).
// R17: FOUR rotating t-buffers -- loads for chunk c+3 issue before computing
// chunk c (slack ~3 chunks > HBM latency). Numerics identical to R16.
#define LPE 8
#define CH 16   // steps per chunk == refresh period

typedef float v2f __attribute__((ext_vector_type(2)));

#if __has_builtin(__builtin_amdgcn_exp2f)
  #define EXP2F(x) __builtin_amdgcn_exp2f(x)
#else
  #define EXP2F(x) exp2f(x)
#endif
#if __has_builtin(__builtin_amdgcn_rcpf)
  #define RCPF(x) __builtin_amdgcn_rcpf(x)
#else
  #define RCPF(x) (1.0f/(x))
#endif

template<int CTRL>
__device__ __forceinline__ float dpp_add(float x) {
    int y = __builtin_amdgcn_update_dpp(0, __float_as_int(x), CTRL, 0xF, 0xF, true);
    return x + __int_as_float(y);
}
// butterfly sum over aligned 8-lane groups; all lanes get the total
__device__ __forceinline__ float red8(float v) {
    v = dpp_add<0xB1>(v);
    v = dpp_add<0x4E>(v);
    v = dpp_add<0x141>(v);
    return v;
}

__device__ __forceinline__ v2f vfma(v2f a, v2f b, v2f c) {
#if __has_builtin(__builtin_elementwise_fma)
    return __builtin_elementwise_fma(a, b, c);
#else
    v2f r; r.x = fmaf(a.x, b.x, c.x); r.y = fmaf(a.y, b.y, c.y); return r;
#endif
}
__device__ __forceinline__ v2f splat(float x) { v2f v; v.x = x; v.y = x; return v; }

#define MEMBAR() __asm__ __volatile__("" ::: "memory")

__global__ __launch_bounds__(256, 1) void ode_scan(
    const float* __restrict__ t,
    const float* __restrict__ Vs,
    const float* __restrict__ Tm,
    const float* __restrict__ C0,
    const float* __restrict__ R0,
    const float* __restrict__ W1,   // (5,10)
    const float* __restrict__ b1,   // (10)
    const float* __restrict__ W2,   // (10,5)
    const float* __restrict__ b2,   // (5)
    float* __restrict__ out,        // (B, N+1, 2)
    int B, int N)
{
    int tid = blockIdx.x * blockDim.x + threadIdx.x;
    int e = tid >> 3;
    int u = tid & 7;
    if (e >= B) return;

    const float S   = 2.88539008177792681472f;   // 2*log2(e)
    const float LN2 = 0.69314718055994530942f;
    float Vv = Vs[e], Tv = Tm[e];

    // Packed per-lane weights for hidden units j0=2u (x), j1=2u+1 (y).
    v2f W0p, W3p, W4p, CCp, V3p, V4p;
    {
        int j0 = 2*u, j1 = 2*u + 1;
        if (j0 < 10) {
            W0p.x = S*W1[j0]; W3p.x = S*W1[30+j0]; W4p.x = S*W1[40+j0];
            CCp.x = S*fmaf(Vv, W1[10+j0], fmaf(Tv, W1[20+j0], b1[j0]));
            V3p.x = -2.0f*W2[5*j0+3]; V4p.x = -2.0f*W2[5*j0+4];
        } else { W0p.x=0.f; W3p.x=0.f; W4p.x=0.f; CCp.x=-60.f; V3p.x=0.f; V4p.x=0.f; }
        if (j1 < 10) {
            W0p.y = S*W1[j1]; W3p.y = S*W1[30+j1]; W4p.y = S*W1[40+j1];
            CCp.y = S*fmaf(Vv, W1[10+j1], fmaf(Tv, W1[20+j1], b1[j1]));
            V3p.y = -2.0f*W2[5*j1+3]; V4p.y = -2.0f*W2[5*j1+4];
        } else { W0p.y=0.f; W3p.y=0.f; W4p.y=0.f; CCp.y=-60.f; V3p.y=0.f; V4p.y=0.f; }
        if (j0 == 10) {
            // constant unit: a=-60 -> r==1.0 exactly, s==0 -> contributes the
            // exact constant to p3,p4 at refresh and ZERO to all C's.
            float c3 = b2[3], c4 = b2[4];
            for (int j = 0; j < 10; ++j) { c3 += W2[5*j+3]; c4 += W2[5*j+4]; }
            V3p.x = c3; V4p.x = c4;
        }
    }

    const v2f ONEv = splat(1.0f);
    // Static coefficient products: M[k][c] = ln2*Wk * Vc  (per-lane v2f)
    v2f W0a = splat(LN2) * W0p, W3a = splat(LN2) * W3p, W4a = splat(LN2) * W4p;
    v2f M30 = W0a * V3p, M33 = W3a * V3p, M34 = W4a * V3p;
    v2f M40 = W0a * V4p, M43 = W3a * V4p, M44 = W4a * V4p;

    const float* trow = t + (size_t)e * (N + 1);
    float* orow = out + (size_t)e * (size_t)(N + 1) * 2;
    v2f CRv;                      // (Cap, Res) packed
    CRv.x = C0[e]; CRv.y = R0[e];
    *(float2*)orow = make_float2(CRv.x, CRv.y);
    float tprev = trow[0];

    // broadcast packed state (uniform across the 8-lane group)
    v2f pv  = splat(0.0f);                      // (p3, p4)
    v2f C0v = splat(0.0f), C3v = splat(0.0f), C4v = splat(0.0f);

    // refresh: exact per-unit r from the bit-exact (tprev,Cap,Res) state,
    // then reduce exact p3,p4 and the six C coefficients (packed).
    auto refresh = [&]() {
        v2f TP = vfma(splat(tprev), W0p, CCp);
        v2f A  = vfma(splat(CRv.y), W4p, vfma(splat(CRv.x), W3p, TP));
        v2f zz; zz.x = EXP2F(A.x); zz.y = EXP2F(A.y);
        v2f dd = zz + ONEv;
        v2f rr; rr.x = RCPF(dd.x); rr.y = RCPF(dd.y);
        v2f ss = vfma(rr, rr, -rr);      // s = r^2 - r
        v2f l3 = rr * V3p, l4 = rr * V4p;
        v2f k30 = ss * M30, k33 = ss * M33, k34 = ss * M34;
        v2f k40 = ss * M40, k43 = ss * M43, k44 = ss * M44;
        pv.x  = red8(l3.x + l3.y);
        pv.y  = red8(l4.x + l4.y);
        C0v.x = red8(k30.x + k30.y);
        C3v.x = red8(k33.x + k33.y);
        C4v.x = red8(k34.x + k34.y);
        C0v.y = red8(k40.x + k40.y);
        C3v.y = red8(k43.x + k43.y);
        C4v.y = red8(k44.x + k44.y);
    };

    // fast step: packed 2x2 linear recurrence; ~5 pk-VALU ops, 3-fma chain.
    auto fstep = [&](float tn, float2& dst) {
        float h  = tn - tprev;
        v2f hv   = splat(h);
        v2f uv   = vfma(splat(pv.y), C4v, vfma(splat(pv.x), C3v, C0v));
        CRv = vfma(hv, pv, CRv);
        pv  = vfma(hv, uv, pv);
        tprev = tn;
        dst = make_float2(CRv.x, CRv.y);
    };

    int i = 1;
    int nch = N / CH;
    if (nch >= 4) {
        float raw0[CH], raw1[CH], raw2[CH], raw3[CH];
        float2 keep[CH];
        int ngrp = nch / 4;
        int lim = N + 1 - CH;

        // prologue: chunks 0,1,2 in flight / resident
#pragma unroll
        for (int m = 0; m < CH; ++m) raw0[m] = trow[1 + m];
#pragma unroll
        for (int m = 0; m < CH; ++m) raw1[m] = trow[1 + CH + m];
#pragma unroll
        for (int m = 0; m < CH; ++m) raw2[m] = trow[1 + 2*CH + m];
        MEMBAR();

        float2* op = (float2*)orow + 1;
        for (int g = 0; g < ngrp; ++g) {
            int c = g * 4;
            // sub-block K: issue loads for chunk c+K+3 into BUFL, compute
            // chunk c+K from BUFC (refresh at head), burst-store.
#define SUB(BUFC, BUFL, K) do {                                             \
        int base = (c + (K) + 3)*CH + 1; if (base > lim) base = lim;        \
        const float* lp = trow + base;                                      \
        _Pragma("unroll")                                                   \
        for (int m = 0; m < CH; ++m) (BUFL)[m] = lp[m];                     \
        MEMBAR();                                                           \
        refresh();                                                          \
        _Pragma("unroll")                                                   \
        for (int m = 0; m < CH; ++m) fstep((BUFC)[m], keep[m]);             \
        MEMBAR();                                                           \
        _Pragma("unroll")                                                   \
        for (int m = 0; m < CH; ++m) op[m] = keep[m];                       \
        op += CH;                                                           \
    } while (0)
            SUB(raw0, raw3, 0);
            SUB(raw1, raw0, 1);
            SUB(raw2, raw1, 2);
            SUB(raw3, raw2, 3);
#undef SUB
        }
        i = ngrp*4*CH + 1;
    }
    // tail (not hit for N=2048): refresh every step (exact)
    for (; i <= N; ++i) {
        refresh();
        fstep(trow[i], *(float2*)(orow + 2*(size_t)i));
    }
}

extern "C" void kernel_launch(void* const* d_in, const int* in_sizes, int n_in,
                              void* d_out, int out_size, void* d_ws, size_t ws_size,
                              hipStream_t stream) {
    const float* t  = (const float*)d_in[0];
    const float* Vs = (const float*)d_in[1];
    const float* Tm = (const float*)d_in[2];
    const float* C0 = (const float*)d_in[3];
    const float* R0 = (const float*)d_in[4];
    const float* W1 = (const float*)d_in[5];
    const float* b1 = (const float*)d_in[6];
    const float* W2 = (const float*)d_in[7];
    const float* b2 = (const float*)d_in[8];
    float* out = (float*)d_out;

    int B = in_sizes[1];
    int N = in_sizes[0] / B - 1;

    int threads = B * LPE;
    dim3 block(256);
    dim3 grid((threads + 255) / 256);
    hipLaunchKernelGGL(ode_scan, grid, block, 0, stream,
                       t, Vs, Tm, C0, R0, W1, b1, W2, b2, out, B, N);
}

// Round 18
// 64.701 us; speedup vs baseline: 2.4058x; 1.0629x over previous
//
#include <hip/hip_runtime.h>

// 8 lanes per batch element; 2 hidden units per lane packed as float2.
// Per-step: packed 2x2 linear recurrence on pv=(p3,p4); six C coefficients
// and exact p3,p4 rebuilt once per 16-step chunk (exp2+rcp + 8 DPP reduces).
// R18: TA-clause diet. Loads: lane u loads its element's t[base+2u..2u+1]
// (2 instrs/chunk); values shared group-wide via ds_swizzle broadcasts (LDS
// pipe). Stores: lane u stashes steps 2u,2u+1 via cndmask and the chunk is
// written with 2 float2 stores. 4-buffer rotation (3 chunks ahead) kept.
#define LPE 8
#define CH 16   // steps per chunk == refresh period

typedef float v2f __attribute__((ext_vector_type(2)));

#if __has_builtin(__builtin_amdgcn_exp2f)
  #define EXP2F(x) __builtin_amdgcn_exp2f(x)
#else
  #define EXP2F(x) exp2f(x)
#endif
#if __has_builtin(__builtin_amdgcn_rcpf)
  #define RCPF(x) __builtin_amdgcn_rcpf(x)
#else
  #define RCPF(x) (1.0f/(x))
#endif

template<int CTRL>
__device__ __forceinline__ float dpp_add(float x) {
    int y = __builtin_amdgcn_update_dpp(0, __float_as_int(x), CTRL, 0xF, 0xF, true);
    return x + __int_as_float(y);
}
// butterfly sum over aligned 8-lane groups; all lanes get the total
__device__ __forceinline__ float red8(float v) {
    v = dpp_add<0xB1>(v);
    v = dpp_add<0x4E>(v);
    v = dpp_add<0x141>(v);
    return v;
}
// broadcast lane (group_base + SRC) to all 8 lanes of its group (BitMode:
// lane' = (lane & 0x18) | SRC within each 32-lane half)
template<int OFF>
__device__ __forceinline__ float swzf(float x) {
    return __int_as_float(__builtin_amdgcn_ds_swizzle(__float_as_int(x), OFF));
}

__device__ __forceinline__ v2f vfma(v2f a, v2f b, v2f c) {
#if __has_builtin(__builtin_elementwise_fma)
    return __builtin_elementwise_fma(a, b, c);
#else
    v2f r; r.x = fmaf(a.x, b.x, c.x); r.y = fmaf(a.y, b.y, c.y); return r;
#endif
}
__device__ __forceinline__ v2f splat(float x) { v2f v; v.x = x; v.y = x; return v; }

#define MEMBAR() __asm__ __volatile__("" ::: "memory")

__global__ __launch_bounds__(256, 1) void ode_scan(
    const float* __restrict__ t,
    const float* __restrict__ Vs,
    const float* __restrict__ Tm,
    const float* __restrict__ C0,
    const float* __restrict__ R0,
    const float* __restrict__ W1,   // (5,10)
    const float* __restrict__ b1,   // (10)
    const float* __restrict__ W2,   // (10,5)
    const float* __restrict__ b2,   // (5)
    float* __restrict__ out,        // (B, N+1, 2)
    int B, int N)
{
    int tid = blockIdx.x * blockDim.x + threadIdx.x;
    int e = tid >> 3;
    int u = tid & 7;
    if (e >= B) return;

    const float S   = 2.88539008177792681472f;   // 2*log2(e)
    const float LN2 = 0.69314718055994530942f;
    float Vv = Vs[e], Tv = Tm[e];

    // Packed per-lane weights for hidden units j0=2u (x), j1=2u+1 (y).
    v2f W0p, W3p, W4p, CCp, V3p, V4p;
    {
        int j0 = 2*u, j1 = 2*u + 1;
        if (j0 < 10) {
            W0p.x = S*W1[j0]; W3p.x = S*W1[30+j0]; W4p.x = S*W1[40+j0];
            CCp.x = S*fmaf(Vv, W1[10+j0], fmaf(Tv, W1[20+j0], b1[j0]));
            V3p.x = -2.0f*W2[5*j0+3]; V4p.x = -2.0f*W2[5*j0+4];
        } else { W0p.x=0.f; W3p.x=0.f; W4p.x=0.f; CCp.x=-60.f; V3p.x=0.f; V4p.x=0.f; }
        if (j1 < 10) {
            W0p.y = S*W1[j1]; W3p.y = S*W1[30+j1]; W4p.y = S*W1[40+j1];
            CCp.y = S*fmaf(Vv, W1[10+j1], fmaf(Tv, W1[20+j1], b1[j1]));
            V3p.y = -2.0f*W2[5*j1+3]; V4p.y = -2.0f*W2[5*j1+4];
        } else { W0p.y=0.f; W3p.y=0.f; W4p.y=0.f; CCp.y=-60.f; V3p.y=0.f; V4p.y=0.f; }
        if (j0 == 10) {
            // constant unit: a=-60 -> r==1.0 exactly, s==0 -> contributes the
            // exact constant to p3,p4 at refresh and ZERO to all C's.
            float c3 = b2[3], c4 = b2[4];
            for (int j = 0; j < 10; ++j) { c3 += W2[5*j+3]; c4 += W2[5*j+4]; }
            V3p.x = c3; V4p.x = c4;
        }
    }

    const v2f ONEv = splat(1.0f);
    // Static coefficient products: M[k][c] = ln2*Wk * Vc  (per-lane v2f)
    v2f W0a = splat(LN2) * W0p, W3a = splat(LN2) * W3p, W4a = splat(LN2) * W4p;
    v2f M30 = W0a * V3p, M33 = W3a * V3p, M34 = W4a * V3p;
    v2f M40 = W0a * V4p, M43 = W3a * V4p, M44 = W4a * V4p;

    const float* trow = t + (size_t)e * (N + 1);
    float* orow = out + (size_t)e * (size_t)(N + 1) * 2;
    v2f CRv;                      // (Cap, Res) packed
    CRv.x = C0[e]; CRv.y = R0[e];
    *(float2*)orow = make_float2(CRv.x, CRv.y);
    float tprev = trow[0];

    // broadcast packed state (uniform across the 8-lane group)
    v2f pv  = splat(0.0f);                      // (p3, p4)
    v2f C0v = splat(0.0f), C3v = splat(0.0f), C4v = splat(0.0f);

    // refresh: exact per-unit r from the bit-exact (tprev,Cap,Res) state,
    // then reduce exact p3,p4 and the six C coefficients (packed).
    auto refresh = [&]() {
        v2f TP = vfma(splat(tprev), W0p, CCp);
        v2f A  = vfma(splat(CRv.y), W4p, vfma(splat(CRv.x), W3p, TP));
        v2f zz; zz.x = EXP2F(A.x); zz.y = EXP2F(A.y);
        v2f dd = zz + ONEv;
        v2f rr; rr.x = RCPF(dd.x); rr.y = RCPF(dd.y);
        v2f ss = vfma(rr, rr, -rr);      // s = r^2 - r
        v2f l3 = rr * V3p, l4 = rr * V4p;
        v2f k30 = ss * M30, k33 = ss * M33, k34 = ss * M34;
        v2f k40 = ss * M40, k43 = ss * M43, k44 = ss * M44;
        pv.x  = red8(l3.x + l3.y);
        pv.y  = red8(l4.x + l4.y);
        C0v.x = red8(k30.x + k30.y);
        C3v.x = red8(k33.x + k33.y);
        C4v.x = red8(k34.x + k34.y);
        C0v.y = red8(k40.x + k40.y);
        C3v.y = red8(k43.x + k43.y);
        C4v.y = red8(k44.x + k44.y);
    };

    // fast step: packed 2x2 linear recurrence; ~5 pk-VALU ops, 3-fma chain.
    auto fstep = [&](float tn) {
        float h  = tn - tprev;
        v2f hv   = splat(h);
        v2f uv   = vfma(splat(pv.y), C4v, vfma(splat(pv.x), C3v, C0v));
        CRv = vfma(hv, pv, CRv);
        pv  = vfma(hv, uv, pv);
        tprev = tn;
    };

    int i = 1;
    int nch = N / CH;
    if (nch >= 4) {
        v2f raw0, raw1, raw2, raw3;    // .x = t[base+2u], .y = t[base+2u+1]
        int ngrp = nch / 4;
        int lim = N + 1 - CH;
        int u2 = 2*u;

        auto loadb = [&](v2f& b, int base) {
            b.x = trow[base + u2];
            b.y = trow[base + u2 + 1];
        };
        loadb(raw0, 1); loadb(raw1, 1 + CH); loadb(raw2, 1 + 2*CH);
        MEMBAR();

        // group-broadcast of step m's t value from the distributed buffer
#define BC(BUF, M) swzf<((((M)>>1)<<5)|0x18)>(((M)&1) ? (BUF).y : (BUF).x)

        for (int g = 0; g < ngrp; ++g) {
            int c = g * 4;
            // sub-block K: load chunk c+K+3 into BUFL; swizzle-broadcast
            // chunk c+K from BUFC; refresh; 16 fsteps with owner-stash;
            // 2 distributed float2 stores.
#define SUB(BUFC, BUFL, K) do {                                             \
        int base = (c + (K) + 3)*CH + 1; if (base > lim) base = lim;        \
        loadb(BUFL, base);                                                  \
        MEMBAR();                                                           \
        float bc[CH];                                                       \
        bc[0]  = BC(BUFC,0);  bc[1]  = BC(BUFC,1);                          \
        bc[2]  = BC(BUFC,2);  bc[3]  = BC(BUFC,3);                          \
        bc[4]  = BC(BUFC,4);  bc[5]  = BC(BUFC,5);                          \
        bc[6]  = BC(BUFC,6);  bc[7]  = BC(BUFC,7);                          \
        bc[8]  = BC(BUFC,8);  bc[9]  = BC(BUFC,9);                          \
        bc[10] = BC(BUFC,10); bc[11] = BC(BUFC,11);                         \
        bc[12] = BC(BUFC,12); bc[13] = BC(BUFC,13);                         \
        bc[14] = BC(BUFC,14); bc[15] = BC(BUFC,15);                         \
        refresh();                                                          \
        v2f st0 = splat(0.0f), st1 = splat(0.0f);                           \
        _Pragma("unroll")                                                   \
        for (int m = 0; m < CH; ++m) {                                      \
            fstep(bc[m]);                                                   \
            bool own = ((m >> 1) == u);                                     \
            if ((m & 1) == 0) st0 = own ? CRv : st0;                        \
            else              st1 = own ? CRv : st1;                        \
        }                                                                   \
        MEMBAR();                                                           \
        float2* sp = (float2*)orow + (size_t)((c + (K))*CH + 1);            \
        sp[u2]     = make_float2(st0.x, st0.y);                             \
        sp[u2 + 1] = make_float2(st1.x, st1.y);                             \
    } while (0)
            SUB(raw0, raw3, 0);
            SUB(raw1, raw0, 1);
            SUB(raw2, raw1, 2);
            SUB(raw3, raw2, 3);
#undef SUB
        }
        i = ngrp*4*CH + 1;
    }
    // tail (not hit for N=2048): refresh every step (exact), direct store
    for (; i <= N; ++i) {
        refresh();
        fstep(trow[i]);
        *(float2*)(orow + 2*(size_t)i) = make_float2(CRv.x, CRv.y);
    }
}

extern "C" void kernel_launch(void* const* d_in, const int* in_sizes, int n_in,
                              void* d_out, int out_size, void* d_ws, size_t ws_size,
                              hipStream_t stream) {
    const float* t  = (const float*)d_in[0];
    const float* Vs = (const float*)d_in[1];
    const float* Tm = (const float*)d_in[2];
    const float* C0 = (const float*)d_in[3];
    const float* R0 = (const float*)d_in[4];
    const float* W1 = (const float*)d_in[5];
    const float* b1 = (const float*)d_in[6];
    const float* W2 = (const float*)d_in[7];
    const float* b2 = (const float*)d_in[8];
    float* out = (float*)d_out;

    int B = in_sizes[1];
    int N = in_sizes[0] / B - 1;

    int threads = B * LPE;
    dim3 block(256);
    dim3 grid((threads + 255) / 256);
    hipLaunchKernelGGL(ode_scan, grid, block, 0, stream,
                       t, Vs, Tm, C0, R0, W1, b1, W2, b2, out, B, N);
}

// Round 19
// 45.198 us; speedup vs baseline: 3.4439x; 1.4315x over previous
//
#include <hip/hip_runtime.h>

// 8 lanes per batch element; 2 hidden units per lane packed as float2.
// R19: PARALLEL chunk evaluation. At each 16-step chunk head, refresh gives
// exact p0=(p3,p4), C coefficients, plus u0 = dp/dtau and w0 = d2p/dtau2.
// Each lane evaluates p at its two OWN steps via the quadratic Taylor
// p(tau) = p0 + tau*u0 + tau^2/2*w0 (tau from its own distributed t-loads),
// forms weighted terms h*p, and the chunk outputs CR_m = CR0 + prefix-sum
// come from ONE 3-stage masked DPP row_shr scan. No per-step serial chain,
// no broadcast swizzles. 4-buffer load rotation (3 chunks ahead) kept.
#define LPE 8
#define CH 16   // steps per chunk == refresh period

typedef float v2f __attribute__((ext_vector_type(2)));

#if __has_builtin(__builtin_amdgcn_exp2f)
  #define EXP2F(x) __builtin_amdgcn_exp2f(x)
#else
  #define EXP2F(x) exp2f(x)
#endif
#if __has_builtin(__builtin_amdgcn_rcpf)
  #define RCPF(x) __builtin_amdgcn_rcpf(x)
#else
  #define RCPF(x) (1.0f/(x))
#endif

template<int CTRL>
__device__ __forceinline__ float dpp_add(float x) {
    int y = __builtin_amdgcn_update_dpp(0, __float_as_int(x), CTRL, 0xF, 0xF, true);
    return x + __int_as_float(y);
}
// butterfly sum over aligned 8-lane groups; all lanes get the total
__device__ __forceinline__ float red8(float v) {
    v = dpp_add<0xB1>(v);
    v = dpp_add<0x4E>(v);
    v = dpp_add<0x141>(v);
    return v;
}
// dpp row_shr:K with bound_ctrl (OOB -> 0)
template<int CTRL>
__device__ __forceinline__ float dpp_shr(float x) {
    int y = __builtin_amdgcn_update_dpp(0, __float_as_int(x), CTRL, 0xF, 0xF, true);
    return __int_as_float(y);
}
// broadcast lane (group_base+7) to all 8 lanes of the group
__device__ __forceinline__ float swz_last(float x) {
    return __int_as_float(__builtin_amdgcn_ds_swizzle(__float_as_int(x), 0x00F8));
}

__device__ __forceinline__ v2f vfma(v2f a, v2f b, v2f c) {
#if __has_builtin(__builtin_elementwise_fma)
    return __builtin_elementwise_fma(a, b, c);
#else
    v2f r; r.x = fmaf(a.x, b.x, c.x); r.y = fmaf(a.y, b.y, c.y); return r;
#endif
}
__device__ __forceinline__ v2f splat(float x) { v2f v; v.x = x; v.y = x; return v; }

#define MEMBAR() __asm__ __volatile__("" ::: "memory")

__global__ __launch_bounds__(256, 1) void ode_scan(
    const float* __restrict__ t,
    const float* __restrict__ Vs,
    const float* __restrict__ Tm,
    const float* __restrict__ C0,
    const float* __restrict__ R0,
    const float* __restrict__ W1,   // (5,10)
    const float* __restrict__ b1,   // (10)
    const float* __restrict__ W2,   // (10,5)
    const float* __restrict__ b2,   // (5)
    float* __restrict__ out,        // (B, N+1, 2)
    int B, int N)
{
    int tid = blockIdx.x * blockDim.x + threadIdx.x;
    int e = tid >> 3;
    int u = tid & 7;
    if (e >= B) return;

    const float S   = 2.88539008177792681472f;   // 2*log2(e)
    const float LN2 = 0.69314718055994530942f;
    float Vv = Vs[e], Tv = Tm[e];

    // Packed per-lane weights for hidden units j0=2u (x), j1=2u+1 (y).
    v2f W0p, W3p, W4p, CCp, V3p, V4p;
    {
        int j0 = 2*u, j1 = 2*u + 1;
        if (j0 < 10) {
            W0p.x = S*W1[j0]; W3p.x = S*W1[30+j0]; W4p.x = S*W1[40+j0];
            CCp.x = S*fmaf(Vv, W1[10+j0], fmaf(Tv, W1[20+j0], b1[j0]));
            V3p.x = -2.0f*W2[5*j0+3]; V4p.x = -2.0f*W2[5*j0+4];
        } else { W0p.x=0.f; W3p.x=0.f; W4p.x=0.f; CCp.x=-60.f; V3p.x=0.f; V4p.x=0.f; }
        if (j1 < 10) {
            W0p.y = S*W1[j1]; W3p.y = S*W1[30+j1]; W4p.y = S*W1[40+j1];
            CCp.y = S*fmaf(Vv, W1[10+j1], fmaf(Tv, W1[20+j1], b1[j1]));
            V3p.y = -2.0f*W2[5*j1+3]; V4p.y = -2.0f*W2[5*j1+4];
        } else { W0p.y=0.f; W3p.y=0.f; W4p.y=0.f; CCp.y=-60.f; V3p.y=0.f; V4p.y=0.f; }
        if (j0 == 10) {
            // constant unit: a=-60 -> r==1.0 exactly, s==0 -> contributes the
            // exact constant to p3,p4 at refresh and ZERO to all C's.
            float c3 = b2[3], c4 = b2[4];
            for (int j = 0; j < 10; ++j) { c3 += W2[5*j+3]; c4 += W2[5*j+4]; }
            V3p.x = c3; V4p.x = c4;
        }
    }

    const v2f ONEv = splat(1.0f);
    v2f W0a = splat(LN2) * W0p, W3a = splat(LN2) * W3p, W4a = splat(LN2) * W4p;
    v2f M30 = W0a * V3p, M33 = W3a * V3p, M34 = W4a * V3p;
    v2f M40 = W0a * V4p, M43 = W3a * V4p, M44 = W4a * V4p;

    const float* trow = t + (size_t)e * (N + 1);
    float* orow = out + (size_t)e * (size_t)(N + 1) * 2;
    v2f CRv;                      // (Cap, Res) packed, group-uniform
    CRv.x = C0[e]; CRv.y = R0[e];
    *(float2*)orow = make_float2(CRv.x, CRv.y);
    float tprev = trow[0];        // group-uniform chunk-start t

    // group-uniform packed state
    v2f pv  = splat(0.0f);                      // (p3, p4)
    v2f C0v = splat(0.0f), C3v = splat(0.0f), C4v = splat(0.0f);

    // refresh: exact per-unit r from (tprev, CRv), reduce p0 and the six C's.
    auto refresh = [&]() {
        v2f TP = vfma(splat(tprev), W0p, CCp);
        v2f A  = vfma(splat(CRv.y), W4p, vfma(splat(CRv.x), W3p, TP));
        v2f zz; zz.x = EXP2F(A.x); zz.y = EXP2F(A.y);
        v2f dd = zz + ONEv;
        v2f rr; rr.x = RCPF(dd.x); rr.y = RCPF(dd.y);
        v2f ss = vfma(rr, rr, -rr);      // s = r^2 - r
        v2f l3 = rr * V3p, l4 = rr * V4p;
        v2f k30 = ss * M30, k33 = ss * M33, k34 = ss * M34;
        v2f k40 = ss * M40, k43 = ss * M43, k44 = ss * M44;
        pv.x  = red8(l3.x + l3.y);
        pv.y  = red8(l4.x + l4.y);
        C0v.x = red8(k30.x + k30.y);
        C3v.x = red8(k33.x + k33.y);
        C4v.x = red8(k34.x + k34.y);
        C0v.y = red8(k40.x + k40.y);
        C3v.y = red8(k43.x + k43.y);
        C4v.y = red8(k44.x + k44.y);
    };

    // sequential exact step (tail only)
    auto fstep = [&](float tn) {
        float h  = tn - tprev;
        v2f hv   = splat(h);
        v2f uv   = vfma(splat(pv.y), C4v, vfma(splat(pv.x), C3v, C0v));
        CRv = vfma(hv, pv, CRv);
        pv  = vfma(hv, uv, pv);
        tprev = tn;
    };

    // inclusive 8-lane segmented scan (3 masked row_shr stages)
    auto scan8 = [&](float x) -> float {
        float s1 = dpp_shr<0x111>(x); x += (u >= 1) ? s1 : 0.0f;
        float s2 = dpp_shr<0x112>(x); x += (u >= 2) ? s2 : 0.0f;
        float s4 = dpp_shr<0x114>(x); x += (u >= 4) ? s4 : 0.0f;
        return x;
    };

    int i = 1;
    int nch = N / CH;
    if (nch >= 4) {
        v2f raw0, raw1, raw2, raw3;    // .x = t[base+2u], .y = t[base+2u+1]
        int ngrp = nch / 4;
        int lim = N + 1 - CH;
        int u2 = 2*u;

        auto loadb = [&](v2f& b, int base) {
            b.x = trow[base + u2];
            b.y = trow[base + u2 + 1];
        };
        loadb(raw0, 1); loadb(raw1, 1 + CH); loadb(raw2, 1 + 2*CH);
        MEMBAR();

        for (int g = 0; g < ngrp; ++g) {
            int c = g * 4;
            // sub-block K: load chunk c+K+3 into BUFL; refresh; quadratic
            // p-eval at the lane's own 2 steps; masked-DPP prefix scan;
            // 2 float2 stores; swizzle-broadcast chunk totals -> CRv, tprev.
#define SUB(BUFC, BUFL, K) do {                                             \
        int base = (c + (K) + 3)*CH + 1; if (base > lim) base = lim;        \
        loadb(BUFL, base);                                                  \
        MEMBAR();                                                           \
        refresh();                                                          \
        v2f uv  = vfma(splat(pv.y), C4v, vfma(splat(pv.x), C3v, C0v));      \
        v2f wv  = vfma(splat(uv.y), C4v, splat(uv.x) * C3v);                \
        v2f wh  = splat(0.5f) * wv;                                         \
        float tA = (BUFC).x, tB = (BUFC).y;                                 \
        float tPm = dpp_shr<0x111>(tB);                                     \
        float tP  = (u >= 1) ? tPm : tprev;                                 \
        float hA  = tA - tP, hB = tB - tA;                                  \
        float tauA = tP - tprev, tauB = tA - tprev;                         \
        v2f pA = vfma(splat(tauA), vfma(splat(tauA), wh, uv), pv);          \
        v2f pB = vfma(splat(tauB), vfma(splat(tauB), wh, uv), pv);          \
        v2f a  = splat(hA) * pA;                                            \
        v2f b  = splat(hB) * pB;                                            \
        v2f sv = a + b;                                                     \
        v2f incl; incl.x = scan8(sv.x); incl.y = scan8(sv.y);               \
        v2f outB = CRv + incl;                                              \
        v2f outA = outB - b;                                                \
        float2* sp = (float2*)orow + (size_t)((c + (K))*CH + 1);            \
        sp[u2]     = make_float2(outA.x, outA.y);                           \
        sp[u2 + 1] = make_float2(outB.x, outB.y);                           \
        v2f tot; tot.x = swz_last(incl.x); tot.y = swz_last(incl.y);        \
        CRv = CRv + tot;                                                    \
        tprev = swz_last(tB);                                               \
        MEMBAR();                                                           \
    } while (0)
            SUB(raw0, raw3, 0);
            SUB(raw1, raw0, 1);
            SUB(raw2, raw1, 2);
            SUB(raw3, raw2, 3);
#undef SUB
        }
        i = ngrp*4*CH + 1;
    }
    // tail (not hit for N=2048): refresh every step (exact), direct store
    for (; i <= N; ++i) {
        refresh();
        fstep(trow[i]);
        *(float2*)(orow + 2*(size_t)i) = make_float2(CRv.x, CRv.y);
    }
}

extern "C" void kernel_launch(void* const* d_in, const int* in_sizes, int n_in,
                              void* d_out, int out_size, void* d_ws, size_t ws_size,
                              hipStream_t stream) {
    const float* t  = (const float*)d_in[0];
    const float* Vs = (const float*)d_in[1];
    const float* Tm = (const float*)d_in[2];
    const float* C0 = (const float*)d_in[3];
    const float* R0 = (const float*)d_in[4];
    const float* W1 = (const float*)d_in[5];
    const float* b1 = (const float*)d_in[6];
    const float* W2 = (const float*)d_in[7];
    const float* b2 = (const float*)d_in[8];
    float* out = (float*)d_out;

    int B = in_sizes[1];
    int N = in_sizes[0] / B - 1;

    int threads = B * LPE;
    dim3 block(256);
    dim3 grid((threads + 255) / 256);
    hipLaunchKernelGGL(ode_scan, grid, block, 0, stream,
                       t, Vs, Tm, C0, R0, W1, b1, W2, b2, out, B, N);
}